// Round 1
// baseline (1739.674 us; speedup 1.0000x reference)
//
#include <hip/hip_runtime.h>

// WindowAttention on MI355X — v1 (correctness-first, bf16 MFMA).
// Pipeline: k_cvt (weights->bf16, bias+mask precombine)
//           4 passes of { k_qkv (QKV GEMM -> bf16 q/k/vT in ws), k_attn (attn + fused proj) }
// ws usage ~104.5 MB (4-pass split to stay small since ws_size is unknown).

#define NTOK   64
#define DIMC   256
#define NWIN   4096
#define PASSES 4
#define PASSW  (NWIN / PASSES)
#define SCALE  0.17677669529663687f   // 32^-0.5

typedef __attribute__((ext_vector_type(8))) short bf8_t;   // 8 x bf16 (4 VGPRs) — doc-verified frag type
typedef __attribute__((ext_vector_type(4))) float f4_t;    // MFMA accumulator

__device__ __forceinline__ ushort f2bf(float x) {
  unsigned u = __float_as_uint(x);
  u = (u + 0x7FFFu + ((u >> 16) & 1u)) >> 16;   // round-to-nearest-even
  return (ushort)u;
}

// ---------------- K0: weight conversion + bias/mask precombine ----------------
// tasks: [0,196608) qkv_w->bf16 ; [196608,262144) proj_w->bf16 ;
//        [262144, 262144+2097152) bm[h][wm][m][n] = bias_table[rel_idx[m,n],h] + mask[wm,m,n]
__global__ __launch_bounds__(256) void k_cvt(
    const float* __restrict__ qkv_w, const float* __restrict__ proj_w,
    const float* __restrict__ bias_table, const int* __restrict__ rel_idx,
    const float* __restrict__ mask,
    ushort* __restrict__ wqkv, ushort* __restrict__ wproj, float* __restrict__ bmo)
{
  const int i = blockIdx.x * 256 + threadIdx.x;
  if (i < 196608) {
    wqkv[i] = f2bf(qkv_w[i]);
  } else if (i < 262144) {
    const int j = i - 196608;
    wproj[j] = f2bf(proj_w[j]);
  } else {
    const int j = i - 262144;                       // j < 2097152
    const int n = j & 63, m = (j >> 6) & 63, wmi = (j >> 12) & 63, h = j >> 18;
    bmo[j] = bias_table[rel_idx[m * 64 + n] * 8 + h] + mask[(wmi * 64 + m) * 64 + n];
  }
}

// ---------------- K1: QKV GEMM per window ----------------
// block = 1 window, 4 waves; wave w handles m-tile w (16 tokens) x all 768 features.
// x tile staged bf16 in LDS (row stride 264 = +16B pad: 2-way bank aliasing only, free).
// Outputs already in MFMA fragment layouts for k_attn:
//   q,k: [wl][h][tok][hd] (A/B frag = 16B contiguous along hd), q pre-scaled.
//   v:   [wl][h][hd][tok] (transposed -> PV B-frag contiguous along tok).
__global__ __launch_bounds__(256) void k_qkv(
    const float* __restrict__ x, const ushort* __restrict__ wqkv,
    const float* __restrict__ qkvb,
    ushort* __restrict__ qws, ushort* __restrict__ kws, ushort* __restrict__ vws,
    int wbase)
{
  __shared__ ushort xs[64 * 264];
  __shared__ float bqs[768];
  const int tid = threadIdx.x;
  const int wl = blockIdx.x;
  const int w = wbase + wl;
  const float* xw = x + (size_t)w * (NTOK * DIMC);

  for (int i = tid; i < 768; i += 256) bqs[i] = qkvb[i];
  {
    const int r = tid >> 2, c0 = (tid & 3) * 64;
    const float4* src = (const float4*)(xw + r * 256 + c0);
    ushort* dst = xs + r * 264 + c0;
    #pragma unroll
    for (int i = 0; i < 16; i++) {
      float4 f = src[i];
      ushort4 u4;
      u4.x = f2bf(f.x); u4.y = f2bf(f.y); u4.z = f2bf(f.z); u4.w = f2bf(f.w);
      *(ushort4*)(dst + i * 4) = u4;
    }
  }
  __syncthreads();

  const int lane = tid & 63, wv = tid >> 6;
  const int lrow = lane & 15, quad = lane >> 4;

  // Preload all 8 A-frags (full K=256) once; reuse over 48 n-tiles.
  bf8_t a[8];
  {
    const ushort* ap = xs + (wv * 16 + lrow) * 264 + quad * 8;
    #pragma unroll
    for (int ks = 0; ks < 8; ks++) a[ks] = *(const bf8_t*)(ap + ks * 32);
  }

  for (int nt = 0; nt < 48; nt++) {
    const int f = nt * 16 + lrow;                 // output feature (B col / D col)
    const ushort* bp = wqkv + f * 256 + quad * 8; // b-frag: 16B contiguous along k
    f4_t acc = {0.f, 0.f, 0.f, 0.f};
    #pragma unroll
    for (int ks = 0; ks < 8; ks++)
      acc = __builtin_amdgcn_mfma_f32_16x16x32_bf16(a[ks], *(const bf8_t*)(bp + ks * 32), acc, 0, 0, 0);
    // D layout: col f = lane&15-based, rows = wv*16 + quad*4 + r
    const float bias = bqs[f];
    const int tok0 = wv * 16 + quad * 4;
    if (f < 256) {            // q (pre-scaled)
      const int h = f >> 5, d = f & 31;
      ushort* dst = qws + ((size_t)wl * 8 + h) * 2048 + d;
      #pragma unroll
      for (int r = 0; r < 4; r++) dst[(tok0 + r) * 32] = f2bf((acc[r] + bias) * SCALE);
    } else if (f < 512) {     // k
      const int h = (f >> 5) & 7, d = f & 31;
      ushort* dst = kws + ((size_t)wl * 8 + h) * 2048 + d;
      #pragma unroll
      for (int r = 0; r < 4; r++) dst[(tok0 + r) * 32] = f2bf(acc[r] + bias);
    } else {                  // v, stored transposed [h][d][tok] -> 8B vector store
      const int h = (f >> 5) & 7, d = f & 31;
      ushort* dst = vws + (((size_t)wl * 8 + h) * 32 + d) * 64 + tok0;
      ushort4 u4;
      u4.x = f2bf(acc[0] + bias); u4.y = f2bf(acc[1] + bias);
      u4.z = f2bf(acc[2] + bias); u4.w = f2bf(acc[3] + bias);
      *(ushort4*)dst = u4;
    }
  }
}

// ---------------- K2: attention + fused output projection per window ----------------
// block = 1 window, 4 waves; wave wv handles heads {2wv, 2wv+1}.
// Per 16-row slab: QK^T (4 MFMA) -> +bm -> quad-group shfl softmax -> P through LDS
// (C/D layout -> A layout) -> PV (4 MFMA, deferred 1/rowsum) -> o into LDS.
// Then whole block: proj GEMM o[64,256] @ proj_w^T + proj_b -> fp32 out.
__global__ __launch_bounds__(256) void k_attn(
    const ushort* __restrict__ qws, const ushort* __restrict__ kws, const ushort* __restrict__ vws,
    const float* __restrict__ bm, const ushort* __restrict__ wproj,
    const float* __restrict__ projb, float* __restrict__ out, int wbase)
{
  __shared__ ushort pbuf[4][16 * 72];   // per-wave P slab, stride 72: b128-aligned, 2-way conflicts only
  __shared__ ushort obuf[64 * 264];     // attention output tile (bf16), +8 pad
  const int tid = threadIdx.x;
  const int lane = tid & 63, wv = tid >> 6;
  const int lrow = lane & 15, quad = lane >> 4;
  const int wl = blockIdx.x;
  const int w = wbase + wl;
  const int wm = w & 63;                // mask window index

  #pragma unroll
  for (int hh = 0; hh < 2; hh++) {
    const int h = wv * 2 + hh;
    const ushort* qh = qws + ((size_t)wl * 8 + h) * 2048;   // [64][32]
    const ushort* kh = kws + ((size_t)wl * 8 + h) * 2048;   // [64][32]
    const ushort* vh = vws + ((size_t)wl * 8 + h) * 2048;   // [32][64] (d-major)
    const float* bmh = bm + ((size_t)h * 64 + wm) * 4096;   // [64][64]

    // Preload K as B-frags (reused over all 4 m-slabs) and V^T B-frags.
    bf8_t kb[4], vb[4];
    #pragma unroll
    for (int nt = 0; nt < 4; nt++)
      kb[nt] = *(const bf8_t*)(kh + (nt * 16 + lrow) * 32 + quad * 8);
    #pragma unroll
    for (int dt = 0; dt < 2; dt++)
      #pragma unroll
      for (int kt = 0; kt < 2; kt++)
        vb[dt * 2 + kt] = *(const bf8_t*)(vh + (dt * 16 + lrow) * 64 + kt * 32 + quad * 8);

    ushort* pb = pbuf[wv];
    #pragma unroll
    for (int mt = 0; mt < 4; mt++) {
      bf8_t qa = *(const bf8_t*)(qh + (mt * 16 + lrow) * 32 + quad * 8);
      f4_t s[4];
      #pragma unroll
      for (int nt = 0; nt < 4; nt++) {
        f4_t z = {0.f, 0.f, 0.f, 0.f};
        s[nt] = __builtin_amdgcn_mfma_f32_16x16x32_bf16(qa, kb[nt], z, 0, 0, 0);
      }
      const int m0 = mt * 16 + quad * 4;   // score rows held by this lane (+r)
      #pragma unroll
      for (int nt = 0; nt < 4; nt++)
        #pragma unroll
        for (int r = 0; r < 4; r++)
          s[nt][r] += bmh[(m0 + r) * 64 + nt * 16 + lrow];
      // Row softmax: 64 values per row live in 16 lanes (one quad group) x 4 nt.
      float rc[4];
      #pragma unroll
      for (int r = 0; r < 4; r++) {
        float mx = fmaxf(fmaxf(s[0][r], s[1][r]), fmaxf(s[2][r], s[3][r]));
        #pragma unroll
        for (int off = 1; off <= 8; off <<= 1) mx = fmaxf(mx, __shfl_xor(mx, off));
        float sum = 0.f;
        #pragma unroll
        for (int nt = 0; nt < 4; nt++) { s[nt][r] = __expf(s[nt][r] - mx); sum += s[nt][r]; }
        #pragma unroll
        for (int off = 1; off <= 8; off <<= 1) sum += __shfl_xor(sum, off);
        rc[r] = 1.f / sum;                 // defer division: PV is linear in P rows
      }
      // P (C/D layout) -> LDS -> A layout
      #pragma unroll
      for (int nt = 0; nt < 4; nt++)
        #pragma unroll
        for (int r = 0; r < 4; r++)
          pb[(quad * 4 + r) * 72 + nt * 16 + lrow] = f2bf(s[nt][r]);
      asm volatile("s_waitcnt lgkmcnt(0)" ::: "memory");  // cross-lane LDS round-trip within wave
      #pragma unroll
      for (int dt = 0; dt < 2; dt++) {
        f4_t acc = {0.f, 0.f, 0.f, 0.f};
        #pragma unroll
        for (int kt = 0; kt < 2; kt++) {
          bf8_t pa = *(const bf8_t*)(pb + lrow * 72 + kt * 32 + quad * 8);
          acc = __builtin_amdgcn_mfma_f32_16x16x32_bf16(pa, vb[dt * 2 + kt], acc, 0, 0, 0);
        }
        #pragma unroll
        for (int r = 0; r < 4; r++)
          obuf[(m0 + r) * 264 + h * 32 + dt * 16 + lrow] = f2bf(acc[r] * rc[r]);
      }
    }
  }
  __syncthreads();

  // Output projection: o[64,256] @ proj_w^T + proj_b. Wave wv -> feature cols [wv*64, wv*64+64).
  #pragma unroll
  for (int mt = 0; mt < 4; mt++) {
    bf8_t a[8];
    const ushort* ap = obuf + (mt * 16 + lrow) * 264 + quad * 8;
    #pragma unroll
    for (int ks = 0; ks < 8; ks++) a[ks] = *(const bf8_t*)(ap + ks * 32);
    #pragma unroll
    for (int nt = 0; nt < 4; nt++) {
      const int f = wv * 64 + nt * 16 + lrow;
      const ushort* bp = wproj + f * 256 + quad * 8;
      f4_t acc = {0.f, 0.f, 0.f, 0.f};
      #pragma unroll
      for (int ks = 0; ks < 8; ks++)
        acc = __builtin_amdgcn_mfma_f32_16x16x32_bf16(a[ks], *(const bf8_t*)(bp + ks * 32), acc, 0, 0, 0);
      const float bias = projb[f];
      float* dst = out + ((size_t)w * 64 + mt * 16 + quad * 4) * 256 + f;
      #pragma unroll
      for (int r = 0; r < 4; r++) dst[(size_t)r * 256] = acc[r] + bias;
    }
  }
}

// ---------------- launch ----------------
extern "C" void kernel_launch(void* const* d_in, const int* in_sizes, int n_in,
                              void* d_out, int out_size, void* d_ws, size_t ws_size,
                              hipStream_t stream) {
  const float* x        = (const float*)d_in[0];
  const float* mask     = (const float*)d_in[1];
  const float* qkv_w    = (const float*)d_in[2];
  const float* qkv_b    = (const float*)d_in[3];
  const float* proj_w   = (const float*)d_in[4];
  const float* proj_b   = (const float*)d_in[5];
  const float* bias_tab = (const float*)d_in[6];
  const int*   rel_idx  = (const int*)d_in[7];
  float* out = (float*)d_out;

  char* ws = (char*)d_ws;
  ushort* wqkv  = (ushort*)(ws + 0);           //   393,216 B
  ushort* wproj = (ushort*)(ws + 393216);      //   131,072 B
  float*  bm    = (float*)(ws + 524288);       // 8,388,608 B  [8][64][64][64]
  ushort* qws   = (ushort*)(ws + 8912896);     // 33,554,432 B [1024][8][64][32] bf16
  ushort* kws   = (ushort*)(ws + 42467328);    // 33,554,432 B
  ushort* vws   = (ushort*)(ws + 76021760);    // 33,554,432 B [1024][8][32][64] bf16
  // total ws required: 109,576,192 B (~104.5 MB)

  k_cvt<<<9216, 256, 0, stream>>>(qkv_w, proj_w, bias_tab, rel_idx, mask, wqkv, wproj, bm);
  for (int p = 0; p < PASSES; p++) {
    const int wbase = p * PASSW;
    k_qkv<<<PASSW, 256, 0, stream>>>(x, wqkv, qkv_b, qws, kws, vws, wbase);
    k_attn<<<PASSW, 256, 0, stream>>>(qws, kws, vws, bm, wproj, proj_b, out, wbase);
  }
}

// Round 2
// 1033.931 us; speedup vs baseline: 1.6826x; 1.6826x over previous
//
#include <hip/hip_runtime.h>

// WindowAttention on MI355X — v2.
// R1 diagnosis: k_qkv/k_attn latency-bound (MfmaUtil 4.8%, HBM 8%) on per-lane
// 16B/scalar L2 gathers of shared operands (weights re-streamed per WAVE, bm scalar).
// v2: pre-swizzle every inter-kernel tensor into per-lane fragment order (all frag
// loads = one coalesced 16B/lane instruction); k_qkv restructured as LDS-staged GEMM
// with global_load_lds width-16 chunk streaming (m97 pattern).

#define NWIN   4096
#define PASSES 4
#define PASSW  (NWIN / PASSES)
#define SCALE  0.17677669529663687f   // 32^-0.5

typedef __attribute__((ext_vector_type(8))) short bf8_t;   // 8 x bf16 (4 VGPRs)
typedef __attribute__((ext_vector_type(4))) float f4_t;    // MFMA accumulator

__device__ __forceinline__ ushort f2bf(float x) {
  unsigned u = __float_as_uint(x);
  u = (u + 0x7FFFu + ((u >> 16) & 1u)) >> 16;   // RNE
  return (ushort)u;
}

__device__ __forceinline__ void async_copy16(const ushort* g, ushort* l) {
  __builtin_amdgcn_global_load_lds(
      (const __attribute__((address_space(1))) unsigned int*)g,
      (__attribute__((address_space(3))) unsigned int*)l, 16, 0, 0);
}

// ---------------- K0: weight/bias pre-swizzle ----------------
// wq_s  [nc(6)][kc(8)][qk(4)][f(128)][j(8)]       bf16 — LDS chunk image order
// wp_s  [wv(4)][nt(4)][ks(8)][quad(4)][lrow(16)][j(8)] bf16 — proj b-frag order
// bm    [h(8)][wm(64)][mt(4)][nt(4)][lane(64)][r(4)]   f32 — C/D-layout float4/lane
__global__ __launch_bounds__(256) void k_cvt(
    const float* __restrict__ qkv_w, const float* __restrict__ proj_w,
    const float* __restrict__ bias_table, const int* __restrict__ rel_idx,
    const float* __restrict__ mask,
    ushort* __restrict__ wq_s, ushort* __restrict__ wp_s, float* __restrict__ bmo)
{
  const int i = blockIdx.x * 256 + threadIdx.x;
  if (i < 196608) {
    const int j = i & 7, f = (i >> 3) & 127, qk = (i >> 10) & 3, kc = (i >> 12) & 7, nc = i >> 15;
    wq_s[i] = f2bf(qkv_w[(nc * 128 + f) * 256 + kc * 32 + qk * 8 + j]);
  } else if (i < 262144) {
    const int o = i - 196608;
    const int j = o & 7, lr = (o >> 3) & 15, qd = (o >> 7) & 3, ks = (o >> 9) & 7,
              nt = (o >> 12) & 3, wvv = o >> 14;
    wp_s[o] = f2bf(proj_w[(wvv * 64 + nt * 16 + lr) * 256 + ks * 32 + qd * 8 + j]);
  } else {
    const int o = i - 262144;                      // < 2097152
    const int r = o & 3, ln = (o >> 2) & 63, nt = (o >> 8) & 3, mt = (o >> 10) & 3,
              wm = (o >> 12) & 63, h = o >> 18;
    const int m = mt * 16 + (ln >> 4) * 4 + r, n = nt * 16 + (ln & 15);
    bmo[o] = bias_table[rel_idx[m * 64 + n] * 8 + h] + mask[(wm * 64 + m) * 64 + n];
  }
}

// ---------------- K1: QKV GEMM per window (LDS-staged) ----------------
// block = 1 window (M=64), 4 waves; wave wv -> m-rows [wv*16, wv*16+16).
// A (x->bf16) LDS-resident for full K=256; B streamed in 8KB (BN=128 x BK=32)
// chunks via global_load_lds from pre-swizzled wq_s. Outputs stored in the exact
// per-lane fragment orders k_attn reads.
__global__ __launch_bounds__(256) void k_qkv(
    const float* __restrict__ x, const ushort* __restrict__ wq_s,
    const float* __restrict__ qkvb,
    ushort* __restrict__ qsw, ushort* __restrict__ ksw, ushort* __restrict__ vsw,
    int wbase)
{
  __shared__ ushort As[64 * 264];   // 33.8 KB, row stride 264 (16B-aligned, 2-way banks)
  __shared__ ushort Bs[4096];       // 8 KB chunk: [qk(4)][f(128)][j(8)]
  __shared__ float bqs[768];
  const int tid = threadIdx.x, lane = tid & 63, wv = tid >> 6;
  const int lrow = lane & 15, quad = lane >> 4;
  const int wl = blockIdx.x;
  const float* xw = x + (size_t)(wbase + wl) * 16384;

  for (int i = tid; i < 768; i += 256) bqs[i] = qkvb[i];
  #pragma unroll
  for (int i = 0; i < 16; i++) {
    const int v = i * 256 + tid;                  // float4 index into x-tile
    float4 f = ((const float4*)xw)[v];
    ushort4 u;
    u.x = f2bf(f.x); u.y = f2bf(f.y); u.z = f2bf(f.z); u.w = f2bf(f.w);
    *(ushort4*)(As + (v >> 6) * 264 + (v & 63) * 4) = u;
  }

  for (int nc = 0; nc < 6; nc++) {
    f4_t acc[8];
    #pragma unroll
    for (int nt = 0; nt < 8; nt++) acc[nt] = (f4_t){0.f, 0.f, 0.f, 0.f};
    for (int kc = 0; kc < 8; kc++) {
      __syncthreads();                             // prior chunk's LDS reads done (+A ready)
      #pragma unroll
      for (int is = 0; is < 2; is++) {
        const ushort* g = wq_s + (size_t)(nc * 8 + kc) * 4096 + ((wv * 2 + is) * 64 + lane) * 8;
        async_copy16(g, Bs + (wv * 2 + is) * 512);
      }
      __syncthreads();                             // chunk landed (barrier drains vmcnt)
      bf8_t a = *(const bf8_t*)(As + (wv * 16 + lrow) * 264 + kc * 32 + quad * 8);
      #pragma unroll
      for (int nt = 0; nt < 8; nt++) {
        bf8_t b = *(const bf8_t*)(Bs + (quad * 128 + nt * 16 + lrow) * 8);
        acc[nt] = __builtin_amdgcn_mfma_f32_16x16x32_bf16(a, b, acc[nt], 0, 0, 0);
      }
    }
    // epilogue for this 128-feature slab: D row = wv*16+quad*4+r, col f = nc*128+nt*16+lrow
    #pragma unroll
    for (int nt = 0; nt < 8; nt++) {
      const int f = nc * 128 + nt * 16 + lrow;
      const float bias = bqs[f];
      if (nc < 2) {          // q (pre-scaled): qsw [wl][h][mt=wv][quad_d(4)][lrow_t(16)][j(8)]
        const int h = f >> 5, d = f & 31;
        ushort* dst = qsw + (((size_t)wl * 8 + h) * 4 + wv) * 512 + (d >> 3) * 128 + (d & 7);
        #pragma unroll
        for (int r = 0; r < 4; r++) dst[(quad * 4 + r) * 8] = f2bf((acc[nt][r] + bias) * SCALE);
      } else if (nc < 4) {   // k: ksw [wl][h][nt_a=wv][quad_d][lrow_t][j]
        const int fk = f - 256, h = fk >> 5, d = fk & 31;
        ushort* dst = ksw + (((size_t)wl * 8 + h) * 4 + wv) * 512 + (d >> 3) * 128 + (d & 7);
        #pragma unroll
        for (int r = 0; r < 4; r++) dst[(quad * 4 + r) * 8] = f2bf(acc[nt][r] + bias);
      } else {               // v^T: vsw [wl][h][dt(2)][kt(2)][quad_t(4)][lrow_d(16)][j(8)]
        const int fv = f - 512, h = fv >> 5, d = fv & 31;
        const int dt = d >> 4, lv = d & 15, kt = wv >> 1;
        ushort* dst = vsw + (((size_t)wl * 8 + h) * 4 + dt * 2 + kt) * 512 + lv * 8;
        #pragma unroll
        for (int r = 0; r < 4; r++) {
          const int tl = (wv & 1) * 16 + quad * 4 + r;   // token within 32-k-step
          dst[(tl >> 3) * 128 + (tl & 7)] = f2bf(acc[nt][r] + bias);
        }
      }
    }
  }
}

// ---------------- K2: attention + fused output projection per window ----------------
// block = 1 window, 4 waves; wave wv handles heads {2wv, 2wv+1}.
// All q/k/v/wproj frag loads are coalesced 16B/lane (pre-swizzled layouts);
// bm is one float4/lane per (mt,nt) in C/D order.
__global__ __launch_bounds__(256) void k_attn(
    const ushort* __restrict__ qsw, const ushort* __restrict__ ksw, const ushort* __restrict__ vsw,
    const float* __restrict__ bm, const ushort* __restrict__ wp_s,
    const float* __restrict__ projb, float* __restrict__ out, int wbase)
{
  __shared__ ushort pbuf[4][16 * 72];   // per-wave P slab (stride 72: aligned b128, 2-way banks)
  __shared__ ushort obuf[64 * 264];     // attention output tile bf16
  const int tid = threadIdx.x, lane = tid & 63, wv = tid >> 6;
  const int lrow = lane & 15, quad = lane >> 4;
  const int wl = blockIdx.x;
  const int w = wbase + wl, wm = w & 63;

  #pragma unroll
  for (int hh = 0; hh < 2; hh++) {
    const int h = wv * 2 + hh;
    const ushort* qh = qsw + ((size_t)wl * 8 + h) * 2048;
    const ushort* kh = ksw + ((size_t)wl * 8 + h) * 2048;
    const ushort* vh = vsw + ((size_t)wl * 8 + h) * 2048;
    const float* bmh = bm + ((size_t)h * 64 + wm) * 4096;   // [mt][nt][lane][4]

    bf8_t kb[4], vb[4];
    #pragma unroll
    for (int nt = 0; nt < 4; nt++)
      kb[nt] = *(const bf8_t*)(kh + nt * 512 + lane * 8);
    #pragma unroll
    for (int dk = 0; dk < 4; dk++)
      vb[dk] = *(const bf8_t*)(vh + dk * 512 + lane * 8);   // dk = dt*2+kt

    ushort* pb = pbuf[wv];
    #pragma unroll
    for (int mt = 0; mt < 4; mt++) {
      bf8_t qa = *(const bf8_t*)(qh + mt * 512 + lane * 8);
      f4_t s[4];
      #pragma unroll
      for (int nt = 0; nt < 4; nt++) {
        f4_t z = {0.f, 0.f, 0.f, 0.f};
        s[nt] = __builtin_amdgcn_mfma_f32_16x16x32_bf16(qa, kb[nt], z, 0, 0, 0);
      }
      #pragma unroll
      for (int nt = 0; nt < 4; nt++) {
        float4 bv = ((const float4*)(bmh + (mt * 4 + nt) * 256))[lane];
        s[nt][0] += bv.x; s[nt][1] += bv.y; s[nt][2] += bv.z; s[nt][3] += bv.w;
      }
      // Row softmax: 64 cols per row live across 16 lanes (quad group) x 4 nt.
      float rc[4];
      #pragma unroll
      for (int r = 0; r < 4; r++) {
        float mx = fmaxf(fmaxf(s[0][r], s[1][r]), fmaxf(s[2][r], s[3][r]));
        #pragma unroll
        for (int off = 1; off <= 8; off <<= 1) mx = fmaxf(mx, __shfl_xor(mx, off));
        float sum = 0.f;
        #pragma unroll
        for (int nt = 0; nt < 4; nt++) { s[nt][r] = __expf(s[nt][r] - mx); sum += s[nt][r]; }
        #pragma unroll
        for (int off = 1; off <= 8; off <<= 1) sum += __shfl_xor(sum, off);
        rc[r] = 1.f / sum;                 // defer division (PV linear in P rows)
      }
      const int m0 = mt * 16 + quad * 4;
      #pragma unroll
      for (int nt = 0; nt < 4; nt++)
        #pragma unroll
        for (int r = 0; r < 4; r++)
          pb[(quad * 4 + r) * 72 + nt * 16 + lrow] = f2bf(s[nt][r]);
      asm volatile("s_waitcnt lgkmcnt(0)" ::: "memory");  // wave-internal LDS round-trip
      #pragma unroll
      for (int dt = 0; dt < 2; dt++) {
        f4_t acc = {0.f, 0.f, 0.f, 0.f};
        #pragma unroll
        for (int kt = 0; kt < 2; kt++) {
          bf8_t pa = *(const bf8_t*)(pb + lrow * 72 + kt * 32 + quad * 8);
          acc = __builtin_amdgcn_mfma_f32_16x16x32_bf16(pa, vb[dt * 2 + kt], acc, 0, 0, 0);
        }
        #pragma unroll
        for (int r = 0; r < 4; r++)
          obuf[(m0 + r) * 264 + h * 32 + dt * 16 + lrow] = f2bf(acc[r] * rc[r]);
      }
    }
  }
  __syncthreads();

  // Output projection: wave wv -> feature cols [wv*64, wv*64+64).
  #pragma unroll
  for (int mt = 0; mt < 4; mt++) {
    bf8_t a[8];
    const ushort* ap = obuf + (mt * 16 + lrow) * 264 + quad * 8;
    #pragma unroll
    for (int ks = 0; ks < 8; ks++) a[ks] = *(const bf8_t*)(ap + ks * 32);
    #pragma unroll
    for (int nt = 0; nt < 4; nt++) {
      f4_t acc = {0.f, 0.f, 0.f, 0.f};
      #pragma unroll
      for (int ks = 0; ks < 8; ks++) {
        bf8_t b = *(const bf8_t*)(wp_s + ((wv * 4 + nt) * 8 + ks) * 512 + lane * 8);
        acc = __builtin_amdgcn_mfma_f32_16x16x32_bf16(a[ks], b, acc, 0, 0, 0);
      }
      const int f = wv * 64 + nt * 16 + lrow;
      const float bias = projb[f];
      float* dst = out + ((size_t)w * 64 + mt * 16 + quad * 4) * 256 + f;
      #pragma unroll
      for (int r = 0; r < 4; r++) dst[(size_t)r * 256] = acc[r] + bias;
    }
  }
}

// ---------------- launch ----------------
extern "C" void kernel_launch(void* const* d_in, const int* in_sizes, int n_in,
                              void* d_out, int out_size, void* d_ws, size_t ws_size,
                              hipStream_t stream) {
  const float* x        = (const float*)d_in[0];
  const float* mask     = (const float*)d_in[1];
  const float* qkv_w    = (const float*)d_in[2];
  const float* qkv_b    = (const float*)d_in[3];
  const float* proj_w   = (const float*)d_in[4];
  const float* proj_b   = (const float*)d_in[5];
  const float* bias_tab = (const float*)d_in[6];
  const int*   rel_idx  = (const int*)d_in[7];
  float* out = (float*)d_out;

  char* ws = (char*)d_ws;
  ushort* wq_s = (ushort*)(ws + 0);           //   393,216 B (swizzled)
  ushort* wp_s = (ushort*)(ws + 393216);      //   131,072 B (swizzled)
  float*  bm   = (float*)(ws + 524288);       // 8,388,608 B (swizzled, fp32)
  ushort* qsw  = (ushort*)(ws + 8912896);     // 33,554,432 B frag-order q
  ushort* ksw  = (ushort*)(ws + 42467328);    // 33,554,432 B frag-order k
  ushort* vsw  = (ushort*)(ws + 76021760);    // 33,554,432 B frag-order v^T
  // total ws required: 109,576,192 B (~104.5 MB) — unchanged from v1 (known to fit)

  k_cvt<<<9216, 256, 0, stream>>>(qkv_w, proj_w, bias_tab, rel_idx, mask, wq_s, wp_s, bm);
  for (int p = 0; p < PASSES; p++) {
    const int wbase = p * PASSW;
    k_qkv<<<PASSW, 256, 0, stream>>>(x, wq_s, qkv_b, qsw, ksw, vsw, wbase);
    k_attn<<<PASSW, 256, 0, stream>>>(qsw, ksw, vsw, bm, wp_s, proj_b, out, wbase);
  }
}